// Round 11
// baseline (375.344 us; speedup 1.0000x reference)
//
#include <hip/hip_runtime.h>
#include <hip/hip_bf16.h>

// Mamba block forward, MI355X. Round 11: LDS-staged register-state scan.
// Round-10: scan_chunk 2x46.6us — per-iter 32B/wave global loads at HBM
// latency (quad-lanes duplicate the same u16; depth-2 prefetch can't cover
// 900cyc). Fix: stage delta+u chunk packed (u32 = delta|u<<16) in LDS via
// wide coalesced loads; serial loop is LDS-only; phase-1 y written back
// through LDS then flushed coalesced. Rest unchanged from round 10.
// L=2048, B=2, D_MODEL=1024, D_INNER=2048, D_STATE=16, DT_RANK=64, D_CONV=4.

#define L_SEQ 2048
#define N_B   2
#define D_M   1024
#define D_I   2048
#define D_ST  16
#define R_DT  64
#define CHNK  16
#define CT    128
#define KS    8           // x_proj split-K chunks (K chunk = 256)

using bf16 = __hip_bfloat16;
typedef unsigned short u16;
typedef unsigned int u32;
typedef u16 u16x8 __attribute__((ext_vector_type(8)));
typedef __bf16 bf16x8 __attribute__((ext_vector_type(8)));
typedef float f32x4 __attribute__((ext_vector_type(4)));

__device__ __forceinline__ float b2f(u16 u) {
    union { u32 i; float f; } x;
    x.i = ((u32)u) << 16;
    return x.f;
}
__device__ __forceinline__ u16 f2b(float f) {
    union { bf16 h; u16 s; } x;
    x.h = __float2bfloat16(f);
    return x.s;
}

__device__ __forceinline__ void load4(const float* p, float* o) {
    const float4 v = *(const float4*)p;
    o[0] = v.x; o[1] = v.y; o[2] = v.z; o[3] = v.w;
}
__device__ __forceinline__ void load4(const bf16* p, float* o) {
    const ushort4 v = *(const ushort4*)(const void*)p;
    o[0] = b2f(v.x); o[1] = b2f(v.y); o[2] = b2f(v.z); o[3] = b2f(v.w);
}

__device__ __forceinline__ float softplus_f(float x) {
    return (x > 20.f) ? x : log1pf(__expf(x));
}
__device__ __forceinline__ float silu_f(float x) {
    return x / (1.f + __expf(-x));
}

__device__ __forceinline__ void gl_lds16(const u16* g, u16* l) {
    __builtin_amdgcn_global_load_lds(
        (const __attribute__((address_space(1))) void*)g,
        (__attribute__((address_space(3))) void*)l, 16, 0, 0);
}

// ---------------- async bf16 MFMA GEMM ----------------
// C[m][n] = sum_k A[m][k]*Wb[n][k]. 128x128 tile, BK=32, XOR-swizzled LDS.
// EPI 0: bf16 bd[t][col], rows r=l*B+b -> t=b*L+l   (in_proj halves)
// EPI 1: fp32 out[l][b][col], rows t=b*L+l           (out_proj)
// EPI 2: bf16 bd[t][col] = softplus(acc + bias[col]) (dt; rows already t)
template <int EPI>
__global__ __launch_bounds__(256) void bgemm(
    const u16* __restrict__ A, int lda,
    const u16* __restrict__ Wb, int ldb, int K,
    u16* __restrict__ bd, float* __restrict__ fout,
    const float* __restrict__ bias)
{
    __shared__ u16 As[128 * 32];
    __shared__ u16 Bs[128 * 32];

    const int tid = threadIdx.x;
    const int m0 = blockIdx.x * 128;
    const int n0 = blockIdx.y * 128;
    const int w  = tid >> 6;
    const int ln = tid & 63;

    const int sr0 = (w << 4) + (ln >> 2);
    const int sr1 = sr0 + 64;
    const int sx  = ln & 3;
    const int qa0 = (sx - (sr0 >> 1)) & 3;
    const int qa1 = (sx - (sr1 >> 1)) & 3;

    const u16* ga0 = A  + (size_t)(m0 + sr0) * lda + qa0 * 8;
    const u16* ga1 = A  + (size_t)(m0 + sr1) * lda + qa1 * 8;
    const u16* gb0 = Wb + (size_t)(n0 + sr0) * ldb + qa0 * 8;
    const u16* gb1 = Wb + (size_t)(n0 + sr1) * ldb + qa1 * 8;
    u16* la0 = As + ((w << 4) + 0) * 32;
    u16* la1 = As + ((w << 4) + 64) * 32;
    u16* lb0 = Bs + ((w << 4) + 0) * 32;
    u16* lb1 = Bs + ((w << 4) + 64) * 32;

    const int wr = (w >> 1) << 6;
    const int wc = (w & 1) << 6;
    const int lm = ln & 15;
    const int qf = ln >> 4;
    int aoff[4], boff[4];
#pragma unroll
    for (int i = 0; i < 4; ++i) {
        const int ra = wr + i * 16 + lm;
        aoff[i] = ra * 32 + (((qf + (ra >> 1)) & 3) << 3);
        const int rb = wc + i * 16 + lm;
        boff[i] = rb * 32 + (((qf + (rb >> 1)) & 3) << 3);
    }

    f32x4 acc[4][4] = {};

    for (int k0 = 0; k0 < K; k0 += 32) {
        if (k0) __syncthreads();
        gl_lds16(ga0 + k0, la0);
        gl_lds16(ga1 + k0, la1);
        gl_lds16(gb0 + k0, lb0);
        gl_lds16(gb1 + k0, lb1);
        __syncthreads();

        bf16x8 af[4], bf[4];
#pragma unroll
        for (int i = 0; i < 4; ++i) af[i] = *(const bf16x8*)&As[aoff[i]];
#pragma unroll
        for (int j = 0; j < 4; ++j) bf[j] = *(const bf16x8*)&Bs[boff[j]];
#pragma unroll
        for (int i = 0; i < 4; ++i)
#pragma unroll
            for (int j = 0; j < 4; ++j)
                acc[i][j] = __builtin_amdgcn_mfma_f32_16x16x32_bf16(
                    af[i], bf[j], acc[i][j], 0, 0, 0);
    }

    const int qr = (ln >> 4) << 2;
    float bv[4];
    if (EPI == 2) {
#pragma unroll
        for (int j = 0; j < 4; ++j) bv[j] = bias[n0 + wc + j * 16 + lm];
    }
#pragma unroll
    for (int i = 0; i < 4; ++i) {
#pragma unroll
        for (int reg = 0; reg < 4; ++reg) {
            const int rg = m0 + wr + i * 16 + qr + reg;
            if (EPI == 0) {
                const int bb = rg & (N_B - 1);
                const int l = rg >> 1;
                const size_t t = (size_t)bb * L_SEQ + l;
#pragma unroll
                for (int j = 0; j < 4; ++j)
                    bd[t * D_I + n0 + wc + j * 16 + lm] = f2b(acc[i][j][reg]);
            } else if (EPI == 1) {
                const int bb = rg >> 11;
                const int l = rg & (L_SEQ - 1);
                const size_t o = ((size_t)l * N_B + bb) * D_M;
#pragma unroll
                for (int j = 0; j < 4; ++j)
                    fout[o + n0 + wc + j * 16 + lm] = acc[i][j][reg];
            } else {
                const size_t t = (size_t)rg;
#pragma unroll
                for (int j = 0; j < 4; ++j)
                    bd[t * D_I + n0 + wc + j * 16 + lm] =
                        f2b(softplus_f(acc[i][j][reg] + bv[j]));
            }
        }
    }
}

// ---------------- x_proj split-K MFMA ----------------
__global__ __launch_bounds__(256) void xproj_k(
    const u16* __restrict__ u, const u16* __restrict__ Wxb,
    float* __restrict__ Part)
{
    __shared__ u16 As[64 * 32];
    __shared__ u16 Bs[96 * 264];

    const int tid = threadIdx.x;
    const int m0 = blockIdx.x * 64;
    const int kc = blockIdx.y;
    const int kbase = kc * 256;

    for (int e = tid; e < 96 * 32; e += 256) {
        const int row = e >> 5, kq = e & 31;
        const u16x8 v = *(const u16x8*)(Wxb + (size_t)row * D_I + kbase + kq * 8);
        *(u16x8*)&Bs[row * 264 + kq * 8] = v;
    }

    const int w  = tid >> 6;
    const int ln = tid & 63;
    const int sr = (w << 4) + (ln >> 2);
    const int sx = ln & 3;
    const int qa = (sx - (sr >> 1)) & 3;
    const u16* ga = u + (size_t)(m0 + sr) * D_I + kbase + qa * 8;
    u16* la = As + (w << 9);

    const int lm = ln & 15;
    const int qf = ln >> 4;
    const int ra = (w << 4) + lm;
    const int aoff = ra * 32 + (((qf + (ra >> 1)) & 3) << 3);

    f32x4 acc[6] = {};

    for (int it = 0; it < 8; ++it) {
        if (it) __syncthreads();
        gl_lds16(ga + it * 32, la);
        __syncthreads();

        const bf16x8 af = *(const bf16x8*)&As[aoff];
#pragma unroll
        for (int j = 0; j < 6; ++j) {
            const bf16x8 bf = *(const bf16x8*)&Bs[(j * 16 + lm) * 264 + it * 32 + qf * 8];
            acc[j] = __builtin_amdgcn_mfma_f32_16x16x32_bf16(af, bf, acc[j], 0, 0, 0);
        }
    }

    const int qr = (ln >> 4) << 2;
#pragma unroll
    for (int j = 0; j < 6; ++j) {
#pragma unroll
        for (int reg = 0; reg < 4; ++reg) {
            const int t = m0 + (w << 4) + qr + reg;
            Part[((size_t)kc * (N_B * L_SEQ) + t) * 96 + j * 16 + lm] = acc[j][reg];
        }
    }
}

__global__ __launch_bounds__(256) void xreduce(
    const float* __restrict__ Part, u16* __restrict__ dtlr,
    float* __restrict__ Bm, float* __restrict__ Cm)
{
    const int e = blockIdx.x * 256 + threadIdx.x;
    const int t = e / 96, c = e - t * 96;
    float s = 0.f;
#pragma unroll
    for (int kc = 0; kc < KS; ++kc)
        s += Part[(size_t)kc * (N_B * L_SEQ * 96) + e];
    if (c < 64)      dtlr[t * 64 + c] = f2b(s);
    else if (c < 80) Bm[t * 16 + (c - 64)] = s;
    else             Cm[t * 16 + (c - 80)] = s;
}

__global__ __launch_bounds__(256) void cvt_k(const float* __restrict__ s,
                                             u16* __restrict__ d)
{
    const size_t i = ((size_t)blockIdx.x * 256 + threadIdx.x) * 8;
    const float4 a = *(const float4*)(s + i);
    const float4 b = *(const float4*)(s + i + 4);
    u16 t[8] = {f2b(a.x), f2b(a.y), f2b(a.z), f2b(a.w),
                f2b(b.x), f2b(b.y), f2b(b.z), f2b(b.w)};
    *(u16x8*)(d + i) = *(const u16x8*)t;
}

__global__ __launch_bounds__(256) void gate_k(u16* __restrict__ y,
                                              const u16* __restrict__ z)
{
    const size_t i = ((size_t)blockIdx.x * 256 + threadIdx.x) * 8;
    u16x8 yv = *(u16x8*)(y + i);
    const u16x8 zv = *(const u16x8*)(z + i);
    u16 t[8];
#pragma unroll
    for (int j = 0; j < 8; ++j)
        t[j] = f2b(b2f(yv[j]) * silu_f(b2f(zv[j])));
    *(u16x8*)(y + i) = *(const u16x8*)t;
}

// ---------------- conv ----------------
__global__ __launch_bounds__(256) void conv_k(
    const bf16* __restrict__ x, const float* __restrict__ cw,
    const float* __restrict__ cb, bf16* __restrict__ xc)
{
    const int t = blockIdx.x;
    const int l = t & (L_SEQ - 1);
#pragma unroll
    for (int it = 0; it < 2; ++it) {
        const int d = ((int)threadIdx.x + it * 256) << 2;
        float w[4][4], bias[4], acc[4];
#pragma unroll
        for (int dd = 0; dd < 4; ++dd)
            load4(cw + (size_t)(d + dd) * 4, w[dd]);
        load4(cb + d, bias);
#pragma unroll
        for (int dd = 0; dd < 4; ++dd) acc[dd] = bias[dd];
#pragma unroll
        for (int j = 0; j < 4; ++j) {
            const int ll = l - 3 + j;
            if (ll >= 0) {
                float xv[4];
                load4(x + (size_t)(t - 3 + j) * D_I + d, xv);
#pragma unroll
                for (int dd = 0; dd < 4; ++dd)
                    acc[dd] = fmaf(xv[dd], w[dd][j], acc[dd]);
            }
        }
        const ushort4 v = make_ushort4(f2b(silu_f(acc[0])), f2b(silu_f(acc[1])),
                                       f2b(silu_f(acc[2])), f2b(silu_f(acc[3])));
        *(ushort4*)(void*)(xc + (size_t)t * D_I + d) = v;
    }
}

// ---------------- chunked scan: LDS-staged register-state ----------------
// Block 256 (64 d x 4 state-groups), grid (D_I/64, B, CHNK).
// LDS: duS[l][dl] u32 = delta | u<<16 (32 KB) + Bs (8 KB) + Cs (8 KB, P1).
// Serial loop: 1x ds_read_b32 (quad broadcast) + b128 B/C broadcasts;
// depth-2 register prefetch. Phase-1 y goes back into duS low halves,
// flushed coalesced at the end.
template <int PHASE>
__global__ __launch_bounds__(256) void scan_chunk(
    bf16* __restrict__ dy, const bf16* __restrict__ u,
    const float* __restrict__ Bm, const float* __restrict__ Cm,
    const float* __restrict__ Alog, const float* __restrict__ Dp,
    float* __restrict__ Pc, float* __restrict__ Qc,
    const float* __restrict__ Sin)
{
    __shared__ u32 duS[CT * 64];
    __shared__ float Bs[CT][D_ST];
    __shared__ float Cs[(PHASE == 1) ? CT : 1][D_ST];

    const int tid = threadIdx.x;
    const int d0 = blockIdx.x * 64;
    const int b  = blockIdx.y;
    const int c  = blockIdx.z;
    const int row0 = b * L_SEQ + c * CT;

    // stage delta+u packed (coalesced 16B loads, 32B LDS writes)
    for (int e = tid; e < CT * 8; e += 256) {
        const int l = e >> 3, g = e & 7;
        const size_t go = (size_t)(row0 + l) * D_I + d0 + g * 8;
        const u16x8 d8 = *(const u16x8*)((const u16*)dy + go);
        const u16x8 u8 = *(const u16x8*)((const u16*)u + go);
        u32 w[8];
#pragma unroll
        for (int j = 0; j < 8; ++j)
            w[j] = (u32)d8[j] | ((u32)u8[j] << 16);
        *(uint4*)&duS[l * 64 + g * 8]     = make_uint4(w[0], w[1], w[2], w[3]);
        *(uint4*)&duS[l * 64 + g * 8 + 4] = make_uint4(w[4], w[5], w[6], w[7]);
    }
    {   // stage B (and C): contiguous fp32, float4-coalesced
        const float4* src = (const float4*)(Bm + (size_t)row0 * D_ST);
        float4* dst = (float4*)Bs;
        for (int e = tid; e < CT * D_ST / 4; e += 256) dst[e] = src[e];
        if (PHASE == 1) {
            const float4* s2 = (const float4*)(Cm + (size_t)row0 * D_ST);
            float4* d2 = (float4*)Cs;
            for (int e = tid; e < CT * D_ST / 4; e += 256) d2[e] = s2[e];
        }
    }
    __syncthreads();

    const int dl = tid >> 2;              // 0..63
    const int d  = d0 + dl;
    const int ns = tid & 3;               // states ns*4 .. ns*4+3
    const size_t pqbase = (((size_t)b * CHNK + c) * D_I + d) * D_ST + ns * 4;

    float Av[4];
    {
        const float4 a4 = *(const float4*)(Alog + (size_t)d * D_ST + ns * 4);
        Av[0] = -__expf(a4.x); Av[1] = -__expf(a4.y);
        Av[2] = -__expf(a4.z); Av[3] = -__expf(a4.w);
    }

    float st[4] = {0.f, 0.f, 0.f, 0.f};
    float P[4]  = {1.f, 1.f, 1.f, 1.f};
    if (PHASE == 1) {
        const float4 s0 = *(const float4*)(Sin + pqbase);
        st[0] = s0.x; st[1] = s0.y; st[2] = s0.z; st[3] = s0.w;
    }
    const float Dd = (PHASE == 1) ? Dp[d] : 0.f;

    u32 w0 = duS[dl];
    u32 w1 = duS[64 + dl];

#pragma unroll 2
    for (int l = 0; l < CT; ++l) {
        const int lp = (l + 2 < CT) ? (l + 2) : (CT - 1);
        const u32 wn = duS[lp * 64 + dl];

        union { u32 i; float f; } dvv, uvv;
        dvv.i = w0 << 16;                 // low half = delta
        uvv.i = w0 & 0xFFFF0000u;         // high half = u (already in place)
        const float dv = dvv.f, uv = uvv.f;
        const float dvu = dv * uv;

        float bn[4], cn[4] = {0.f, 0.f, 0.f, 0.f};
        {
            const float4 b4 = *(const float4*)&Bs[l][ns * 4];
            bn[0] = b4.x; bn[1] = b4.y; bn[2] = b4.z; bn[3] = b4.w;
        }
        if (PHASE == 1) {
            const float4 c4 = *(const float4*)&Cs[l][ns * 4];
            cn[0] = c4.x; cn[1] = c4.y; cn[2] = c4.z; cn[3] = c4.w;
        }

        float y = 0.f;
#pragma unroll
        for (int j = 0; j < 4; ++j) {
            const float dA = __expf(dv * Av[j]);
            if (PHASE == 0) P[j] *= dA;
            st[j] = fmaf(st[j], dA, dvu * bn[j]);
            if (PHASE == 1) y = fmaf(st[j], cn[j], y);
        }
        if (PHASE == 1) {
            y += __shfl_xor(y, 1);        // quad-level reduce (DPP)
            y += __shfl_xor(y, 2);
            if (ns == 0)                  // y -> low half of duS[l][dl]
                ((u16*)duS)[(l * 64 + dl) * 2] = f2b(y + uv * Dd);
        }
        w0 = w1; w1 = wn;
    }

    if (PHASE == 0) {
        *(float4*)(Pc + pqbase) = make_float4(P[0], P[1], P[2], P[3]);
        *(float4*)(Qc + pqbase) = make_float4(st[0], st[1], st[2], st[3]);
    } else {
        __syncthreads();
        // coalesced y writeback over delta
        for (int e = tid; e < CT * 8; e += 256) {
            const int l = e >> 3, g = e & 7;
            u16 t[8];
#pragma unroll
            for (int j = 0; j < 8; ++j)
                t[j] = (u16)(duS[l * 64 + g * 8 + j] & 0xFFFFu);
            *(u16x8*)((u16*)dy + (size_t)(row0 + l) * D_I + d0 + g * 8) =
                *(const u16x8*)t;
        }
    }
}

__global__ __launch_bounds__(256) void scan_comb(
    const float* __restrict__ Pc, const float* __restrict__ Qc,
    float* __restrict__ Sin)
{
    const int b = blockIdx.y;
    const int d = blockIdx.x * 16 + (threadIdx.x >> 4);
    const int n = threadIdx.x & 15;
    float s = 0.f;
#pragma unroll
    for (int c = 0; c < CHNK; ++c) {
        const size_t idx = (((size_t)b * CHNK + c) * D_I + d) * D_ST + n;
        Sin[idx] = s;
        s = fmaf(s, Pc[idx], Qc[idx]);
    }
}

__global__ void zfill(float* o) {
    o[(size_t)blockIdx.x * 256 + threadIdx.x] = 0.f;
}

extern "C" void kernel_launch(void* const* d_in, const int* in_sizes, int n_in,
                              void* d_out, int out_size, void* d_ws, size_t ws_size,
                              hipStream_t stream)
{
    const float* hs   = (const float*)d_in[0];
    const float* Win  = (const float*)d_in[1];
    const float* cw   = (const float*)d_in[2];
    const float* cb   = (const float*)d_in[3];
    const float* Wx   = (const float*)d_in[4];
    const float* Wdt  = (const float*)d_in[5];
    const float* dtb  = (const float*)d_in[6];
    const float* Alog = (const float*)d_in[7];
    const float* Dp   = (const float*)d_in[8];
    const float* Wout = (const float*)d_in[9];
    float* out = (float*)d_out;

    const size_t SZ = (size_t)N_B * L_SEQ * D_I;        // 8,388,608
    const size_t NT = (size_t)N_B * L_SEQ;              // 4096 tokens
    const size_t NHS   = NT * D_M;
    const size_t NWIN  = (size_t)2 * D_I * D_M;
    const size_t NWOUT = (size_t)D_M * D_I;
    const size_t NWX   = (size_t)96 * D_I;
    const size_t NWDT  = (size_t)D_I * R_DT;
    const size_t NEED = SZ * 2 * sizeof(bf16)
                      + (NHS + NWIN + NWOUT + NWX + NWDT + NT * R_DT) * sizeof(u16)
                      + NT * 2 * D_ST * sizeof(float);
    if (ws_size < NEED) {   // diagnostic: absmax would print exactly 2.375
        zfill<<<dim3((unsigned)((size_t)out_size / 256)), 256, 0, stream>>>(out);
        return;
    }

    bf16* RA   = (bf16*)d_ws;          // x -> delta -> y(gated)
    bf16* RB   = RA + SZ;              // u -> z
    u16* bhs   = (u16*)(RB + SZ);
    u16* bWin  = bhs + NHS;
    u16* bWout = bWin + NWIN;
    u16* bWx   = bWout + NWOUT;
    u16* bWdt  = bWx + NWX;
    u16* dtlr  = bWdt + NWDT;
    float* Bm  = (float*)(dtlr + NT * R_DT);
    float* Cm  = Bm + NT * D_ST;
    float* Part = out;                 // d_out scratch (dead until final GEMM)
    const size_t PQ = (size_t)N_B * CHNK * D_I * D_ST;
    float* Pc  = out;
    float* Qc  = Pc + PQ;
    float* Sin = Qc + PQ;

    // 0) one-time fp32 -> bf16 conversions
    cvt_k<<<dim3((unsigned)(NHS / 2048)), 256, 0, stream>>>(hs, bhs);
    cvt_k<<<dim3((unsigned)(NWIN / 2048)), 256, 0, stream>>>(Win, bWin);
    cvt_k<<<dim3((unsigned)(NWOUT / 2048)), 256, 0, stream>>>(Wout, bWout);
    cvt_k<<<dim3((unsigned)(NWX / 2048)), 256, 0, stream>>>(Wx, bWx);
    cvt_k<<<dim3((unsigned)(NWDT / 2048)), 256, 0, stream>>>(Wdt, bWdt);
    // 1) in_proj x-half
    bgemm<0><<<dim3(32, 16), 256, 0, stream>>>(
        bhs, D_M, bWin, D_M, D_M, (u16*)RA, nullptr, nullptr);
    // 2) conv + silu: RA(x) -> RB(u)
    conv_k<<<dim3(N_B * L_SEQ), 256, 0, stream>>>(RA, cw, cb, RB);
    // 3) x_proj split-K -> Part -> reduce
    xproj_k<<<dim3(64, KS), 256, 0, stream>>>((const u16*)RB, bWx, Part);
    xreduce<<<dim3((unsigned)(NT * 96 / 256)), 256, 0, stream>>>(Part, dtlr, Bm, Cm);
    // 4) dt -> delta (RA)
    bgemm<2><<<dim3(32, 16), 256, 0, stream>>>(
        dtlr, R_DT, bWdt, R_DT, R_DT, (u16*)RA, nullptr, dtb);
    // 5) chunked scan
    scan_chunk<0><<<dim3(D_I / 64, N_B, CHNK), 256, 0, stream>>>(
        RA, RB, Bm, Cm, Alog, Dp, Pc, Qc, nullptr);
    scan_comb<<<dim3(D_I / 16, N_B), 256, 0, stream>>>(Pc, Qc, Sin);
    scan_chunk<1><<<dim3(D_I / 64, N_B, CHNK), 256, 0, stream>>>(
        RA, RB, Bm, Cm, Alog, Dp, nullptr, nullptr, Sin);
    // 6) in_proj z-half -> RB
    bgemm<0><<<dim3(32, 16), 256, 0, stream>>>(
        bhs, D_M, bWin + (size_t)D_I * D_M, D_M, D_M, (u16*)RB, nullptr, nullptr);
    // 6b) gate: y *= silu(z)
    gate_k<<<dim3((unsigned)(SZ / 2048)), 256, 0, stream>>>((u16*)RA, (const u16*)RB);
    // 7) out_proj -> d_out
    bgemm<1><<<dim3(32, 8), 256, 0, stream>>>(
        (const u16*)RA, D_I, bWout, D_I, D_I, nullptr, out, nullptr);
}

// Round 12
// 357.594 us; speedup vs baseline: 1.0496x; 1.0496x over previous
//
#include <hip/hip_runtime.h>
#include <hip/hip_bf16.h>

// Mamba block forward, MI355X. Round 12: scan occupancy fix.
// Round-11 regressed (46.6 -> 62us/phase): 48KB LDS -> 3 blocks/CU, occ 21%.
// Fix: CT=64, CHNK=32 -> 25.4KB LDS -> 6 blocks/CU (~75% occ), 2048 blocks;
// duS stride 68 (write conflicts 16->8-way, reads clean); scan_comb loads all
// P/Q into registers first (chain = 32 FMA, not 32 global loads).
// Sin aliases Pc in d_out (read-before-write in comb); Pc+Qc = 16MB <= out.
// L=2048, B=2, D_MODEL=1024, D_INNER=2048, D_STATE=16, DT_RANK=64, D_CONV=4.

#define L_SEQ 2048
#define N_B   2
#define D_M   1024
#define D_I   2048
#define D_ST  16
#define R_DT  64
#define CHNK  32
#define CT    64
#define KS    8           // x_proj split-K chunks (K chunk = 256)
#define DUS   68          // duS row stride (u32 words)

using bf16 = __hip_bfloat16;
typedef unsigned short u16;
typedef unsigned int u32;
typedef u16 u16x8 __attribute__((ext_vector_type(8)));
typedef __bf16 bf16x8 __attribute__((ext_vector_type(8)));
typedef float f32x4 __attribute__((ext_vector_type(4)));

__device__ __forceinline__ float b2f(u16 u) {
    union { u32 i; float f; } x;
    x.i = ((u32)u) << 16;
    return x.f;
}
__device__ __forceinline__ u16 f2b(float f) {
    union { bf16 h; u16 s; } x;
    x.h = __float2bfloat16(f);
    return x.s;
}

__device__ __forceinline__ void load4(const float* p, float* o) {
    const float4 v = *(const float4*)p;
    o[0] = v.x; o[1] = v.y; o[2] = v.z; o[3] = v.w;
}
__device__ __forceinline__ void load4(const bf16* p, float* o) {
    const ushort4 v = *(const ushort4*)(const void*)p;
    o[0] = b2f(v.x); o[1] = b2f(v.y); o[2] = b2f(v.z); o[3] = b2f(v.w);
}

__device__ __forceinline__ float softplus_f(float x) {
    return (x > 20.f) ? x : log1pf(__expf(x));
}
__device__ __forceinline__ float silu_f(float x) {
    return x / (1.f + __expf(-x));
}

__device__ __forceinline__ void gl_lds16(const u16* g, u16* l) {
    __builtin_amdgcn_global_load_lds(
        (const __attribute__((address_space(1))) void*)g,
        (__attribute__((address_space(3))) void*)l, 16, 0, 0);
}

// ---------------- async bf16 MFMA GEMM ----------------
// C[m][n] = sum_k A[m][k]*Wb[n][k]. 128x128 tile, BK=32, XOR-swizzled LDS.
// EPI 0: bf16 bd[t][col], rows r=l*B+b -> t=b*L+l   (in_proj halves)
// EPI 1: fp32 out[l][b][col], rows t=b*L+l           (out_proj)
// EPI 2: bf16 bd[t][col] = softplus(acc + bias[col]) (dt; rows already t)
template <int EPI>
__global__ __launch_bounds__(256) void bgemm(
    const u16* __restrict__ A, int lda,
    const u16* __restrict__ Wb, int ldb, int K,
    u16* __restrict__ bd, float* __restrict__ fout,
    const float* __restrict__ bias)
{
    __shared__ u16 As[128 * 32];
    __shared__ u16 Bs[128 * 32];

    const int tid = threadIdx.x;
    const int m0 = blockIdx.x * 128;
    const int n0 = blockIdx.y * 128;
    const int w  = tid >> 6;
    const int ln = tid & 63;

    const int sr0 = (w << 4) + (ln >> 2);
    const int sr1 = sr0 + 64;
    const int sx  = ln & 3;
    const int qa0 = (sx - (sr0 >> 1)) & 3;
    const int qa1 = (sx - (sr1 >> 1)) & 3;

    const u16* ga0 = A  + (size_t)(m0 + sr0) * lda + qa0 * 8;
    const u16* ga1 = A  + (size_t)(m0 + sr1) * lda + qa1 * 8;
    const u16* gb0 = Wb + (size_t)(n0 + sr0) * ldb + qa0 * 8;
    const u16* gb1 = Wb + (size_t)(n0 + sr1) * ldb + qa1 * 8;
    u16* la0 = As + ((w << 4) + 0) * 32;
    u16* la1 = As + ((w << 4) + 64) * 32;
    u16* lb0 = Bs + ((w << 4) + 0) * 32;
    u16* lb1 = Bs + ((w << 4) + 64) * 32;

    const int wr = (w >> 1) << 6;
    const int wc = (w & 1) << 6;
    const int lm = ln & 15;
    const int qf = ln >> 4;
    int aoff[4], boff[4];
#pragma unroll
    for (int i = 0; i < 4; ++i) {
        const int ra = wr + i * 16 + lm;
        aoff[i] = ra * 32 + (((qf + (ra >> 1)) & 3) << 3);
        const int rb = wc + i * 16 + lm;
        boff[i] = rb * 32 + (((qf + (rb >> 1)) & 3) << 3);
    }

    f32x4 acc[4][4] = {};

    for (int k0 = 0; k0 < K; k0 += 32) {
        if (k0) __syncthreads();
        gl_lds16(ga0 + k0, la0);
        gl_lds16(ga1 + k0, la1);
        gl_lds16(gb0 + k0, lb0);
        gl_lds16(gb1 + k0, lb1);
        __syncthreads();

        bf16x8 af[4], bf[4];
#pragma unroll
        for (int i = 0; i < 4; ++i) af[i] = *(const bf16x8*)&As[aoff[i]];
#pragma unroll
        for (int j = 0; j < 4; ++j) bf[j] = *(const bf16x8*)&Bs[boff[j]];
#pragma unroll
        for (int i = 0; i < 4; ++i)
#pragma unroll
            for (int j = 0; j < 4; ++j)
                acc[i][j] = __builtin_amdgcn_mfma_f32_16x16x32_bf16(
                    af[i], bf[j], acc[i][j], 0, 0, 0);
    }

    const int qr = (ln >> 4) << 2;
    float bv[4];
    if (EPI == 2) {
#pragma unroll
        for (int j = 0; j < 4; ++j) bv[j] = bias[n0 + wc + j * 16 + lm];
    }
#pragma unroll
    for (int i = 0; i < 4; ++i) {
#pragma unroll
        for (int reg = 0; reg < 4; ++reg) {
            const int rg = m0 + wr + i * 16 + qr + reg;
            if (EPI == 0) {
                const int bb = rg & (N_B - 1);
                const int l = rg >> 1;
                const size_t t = (size_t)bb * L_SEQ + l;
#pragma unroll
                for (int j = 0; j < 4; ++j)
                    bd[t * D_I + n0 + wc + j * 16 + lm] = f2b(acc[i][j][reg]);
            } else if (EPI == 1) {
                const int bb = rg >> 11;
                const int l = rg & (L_SEQ - 1);
                const size_t o = ((size_t)l * N_B + bb) * D_M;
#pragma unroll
                for (int j = 0; j < 4; ++j)
                    fout[o + n0 + wc + j * 16 + lm] = acc[i][j][reg];
            } else {
                const size_t t = (size_t)rg;
#pragma unroll
                for (int j = 0; j < 4; ++j)
                    bd[t * D_I + n0 + wc + j * 16 + lm] =
                        f2b(softplus_f(acc[i][j][reg] + bv[j]));
            }
        }
    }
}

// ---------------- x_proj split-K MFMA ----------------
__global__ __launch_bounds__(256) void xproj_k(
    const u16* __restrict__ u, const u16* __restrict__ Wxb,
    float* __restrict__ Part)
{
    __shared__ u16 As[64 * 32];
    __shared__ u16 Bs[96 * 264];

    const int tid = threadIdx.x;
    const int m0 = blockIdx.x * 64;
    const int kc = blockIdx.y;
    const int kbase = kc * 256;

    for (int e = tid; e < 96 * 32; e += 256) {
        const int row = e >> 5, kq = e & 31;
        const u16x8 v = *(const u16x8*)(Wxb + (size_t)row * D_I + kbase + kq * 8);
        *(u16x8*)&Bs[row * 264 + kq * 8] = v;
    }

    const int w  = tid >> 6;
    const int ln = tid & 63;
    const int sr = (w << 4) + (ln >> 2);
    const int sx = ln & 3;
    const int qa = (sx - (sr >> 1)) & 3;
    const u16* ga = u + (size_t)(m0 + sr) * D_I + kbase + qa * 8;
    u16* la = As + (w << 9);

    const int lm = ln & 15;
    const int qf = ln >> 4;
    const int ra = (w << 4) + lm;
    const int aoff = ra * 32 + (((qf + (ra >> 1)) & 3) << 3);

    f32x4 acc[6] = {};

    for (int it = 0; it < 8; ++it) {
        if (it) __syncthreads();
        gl_lds16(ga + it * 32, la);
        __syncthreads();

        const bf16x8 af = *(const bf16x8*)&As[aoff];
#pragma unroll
        for (int j = 0; j < 6; ++j) {
            const bf16x8 bf = *(const bf16x8*)&Bs[(j * 16 + lm) * 264 + it * 32 + qf * 8];
            acc[j] = __builtin_amdgcn_mfma_f32_16x16x32_bf16(af, bf, acc[j], 0, 0, 0);
        }
    }

    const int qr = (ln >> 4) << 2;
#pragma unroll
    for (int j = 0; j < 6; ++j) {
#pragma unroll
        for (int reg = 0; reg < 4; ++reg) {
            const int t = m0 + (w << 4) + qr + reg;
            Part[((size_t)kc * (N_B * L_SEQ) + t) * 96 + j * 16 + lm] = acc[j][reg];
        }
    }
}

__global__ __launch_bounds__(256) void xreduce(
    const float* __restrict__ Part, u16* __restrict__ dtlr,
    float* __restrict__ Bm, float* __restrict__ Cm)
{
    const int e = blockIdx.x * 256 + threadIdx.x;
    const int t = e / 96, c = e - t * 96;
    float s = 0.f;
#pragma unroll
    for (int kc = 0; kc < KS; ++kc)
        s += Part[(size_t)kc * (N_B * L_SEQ * 96) + e];
    if (c < 64)      dtlr[t * 64 + c] = f2b(s);
    else if (c < 80) Bm[t * 16 + (c - 64)] = s;
    else             Cm[t * 16 + (c - 80)] = s;
}

__global__ __launch_bounds__(256) void cvt_k(const float* __restrict__ s,
                                             u16* __restrict__ d)
{
    const size_t i = ((size_t)blockIdx.x * 256 + threadIdx.x) * 8;
    const float4 a = *(const float4*)(s + i);
    const float4 b = *(const float4*)(s + i + 4);
    u16 t[8] = {f2b(a.x), f2b(a.y), f2b(a.z), f2b(a.w),
                f2b(b.x), f2b(b.y), f2b(b.z), f2b(b.w)};
    *(u16x8*)(d + i) = *(const u16x8*)t;
}

__global__ __launch_bounds__(256) void gate_k(u16* __restrict__ y,
                                              const u16* __restrict__ z)
{
    const size_t i = ((size_t)blockIdx.x * 256 + threadIdx.x) * 8;
    u16x8 yv = *(u16x8*)(y + i);
    const u16x8 zv = *(const u16x8*)(z + i);
    u16 t[8];
#pragma unroll
    for (int j = 0; j < 8; ++j)
        t[j] = f2b(b2f(yv[j]) * silu_f(b2f(zv[j])));
    *(u16x8*)(y + i) = *(const u16x8*)t;
}

// ---------------- conv ----------------
__global__ __launch_bounds__(256) void conv_k(
    const bf16* __restrict__ x, const float* __restrict__ cw,
    const float* __restrict__ cb, bf16* __restrict__ xc)
{
    const int t = blockIdx.x;
    const int l = t & (L_SEQ - 1);
#pragma unroll
    for (int it = 0; it < 2; ++it) {
        const int d = ((int)threadIdx.x + it * 256) << 2;
        float w[4][4], bias[4], acc[4];
#pragma unroll
        for (int dd = 0; dd < 4; ++dd)
            load4(cw + (size_t)(d + dd) * 4, w[dd]);
        load4(cb + d, bias);
#pragma unroll
        for (int dd = 0; dd < 4; ++dd) acc[dd] = bias[dd];
#pragma unroll
        for (int j = 0; j < 4; ++j) {
            const int ll = l - 3 + j;
            if (ll >= 0) {
                float xv[4];
                load4(x + (size_t)(t - 3 + j) * D_I + d, xv);
#pragma unroll
                for (int dd = 0; dd < 4; ++dd)
                    acc[dd] = fmaf(xv[dd], w[dd][j], acc[dd]);
            }
        }
        const ushort4 v = make_ushort4(f2b(silu_f(acc[0])), f2b(silu_f(acc[1])),
                                       f2b(silu_f(acc[2])), f2b(silu_f(acc[3])));
        *(ushort4*)(void*)(xc + (size_t)t * D_I + d) = v;
    }
}

// ---------------- chunked scan: LDS-staged, CT=64 ----------------
// Block 256 (64 d x 4 state-groups), grid (D_I/64, B, CHNK=32) = 2048 blocks.
// LDS: duS[l][dl] u32 = delta | u<<16, row stride 68 (25.4KB total w/ Bs+Cs
// -> 6 blocks/CU). Serial loop LDS-only. Phase-1 y back into duS low halves,
// flushed coalesced.
template <int PHASE>
__global__ __launch_bounds__(256) void scan_chunk(
    bf16* __restrict__ dy, const bf16* __restrict__ u,
    const float* __restrict__ Bm, const float* __restrict__ Cm,
    const float* __restrict__ Alog, const float* __restrict__ Dp,
    float* __restrict__ Pc, float* __restrict__ Qc,
    const float* __restrict__ Sin)
{
    __shared__ u32 duS[CT * DUS];
    __shared__ float Bs[CT][D_ST];
    __shared__ float Cs[(PHASE == 1) ? CT : 1][D_ST];

    const int tid = threadIdx.x;
    const int d0 = blockIdx.x * 64;
    const int b  = blockIdx.y;
    const int c  = blockIdx.z;
    const int row0 = b * L_SEQ + c * CT;

    // stage delta+u packed (coalesced 16B global loads)
    for (int e = tid; e < CT * 8; e += 256) {
        const int l = e >> 3, g = e & 7;
        const size_t go = (size_t)(row0 + l) * D_I + d0 + g * 8;
        const u16x8 d8 = *(const u16x8*)((const u16*)dy + go);
        const u16x8 u8 = *(const u16x8*)((const u16*)u + go);
        u32 w[8];
#pragma unroll
        for (int j = 0; j < 8; ++j)
            w[j] = (u32)d8[j] | ((u32)u8[j] << 16);
        *(uint4*)&duS[l * DUS + g * 8]     = make_uint4(w[0], w[1], w[2], w[3]);
        *(uint4*)&duS[l * DUS + g * 8 + 4] = make_uint4(w[4], w[5], w[6], w[7]);
    }
    {   // stage B (and C)
        const float4* src = (const float4*)(Bm + (size_t)row0 * D_ST);
        float4* dst = (float4*)Bs;
        for (int e = tid; e < CT * D_ST / 4; e += 256) dst[e] = src[e];
        if (PHASE == 1) {
            const float4* s2 = (const float4*)(Cm + (size_t)row0 * D_ST);
            float4* d2 = (float4*)Cs;
            for (int e = tid; e < CT * D_ST / 4; e += 256) d2[e] = s2[e];
        }
    }
    __syncthreads();

    const int dl = tid >> 2;              // 0..63
    const int d  = d0 + dl;
    const int ns = tid & 3;               // states ns*4 .. ns*4+3
    const size_t pqbase = (((size_t)b * CHNK + c) * D_I + d) * D_ST + ns * 4;

    float Av[4];
    {
        const float4 a4 = *(const float4*)(Alog + (size_t)d * D_ST + ns * 4);
        Av[0] = -__expf(a4.x); Av[1] = -__expf(a4.y);
        Av[2] = -__expf(a4.z); Av[3] = -__expf(a4.w);
    }

    float st[4] = {0.f, 0.f, 0.f, 0.f};
    float P[4]  = {1.f, 1.f, 1.f, 1.f};
    if (PHASE == 1) {
        const float4 s0 = *(const float4*)(Sin + pqbase);
        st[0] = s0.x; st[1] = s0.y; st[2] = s0.z; st[3] = s0.w;
    }
    const float Dd = (PHASE == 1) ? Dp[d] : 0.f;

#pragma unroll 2
    for (int l = 0; l < CT; ++l) {
        const u32 w0 = duS[l * DUS + dl];
        union { u32 i; float f; } dvv, uvv;
        dvv.i = w0 << 16;                 // low half = delta
        uvv.i = w0 & 0xFFFF0000u;         // high half = u
        const float dv = dvv.f, uv = uvv.f;
        const float dvu = dv * uv;

        float bn[4], cn[4] = {0.f, 0.f, 0.f, 0.f};
        {
            const float4 b4 = *(const float4*)&Bs[l][ns * 4];
            bn[0] = b4.x; bn[1] = b4.y; bn[2] = b4.z; bn[3] = b4.w;
        }
        if (PHASE == 1) {
            const float4 c4 = *(const float4*)&Cs[l][ns * 4];
            cn[0] = c4.x; cn[1] = c4.y; cn[2] = c4.z; cn[3] = c4.w;
        }

        float y = 0.f;
#pragma unroll
        for (int j = 0; j < 4; ++j) {
            const float dA = __expf(dv * Av[j]);
            if (PHASE == 0) P[j] *= dA;
            st[j] = fmaf(st[j], dA, dvu * bn[j]);
            if (PHASE == 1) y = fmaf(st[j], cn[j], y);
        }
        if (PHASE == 1) {
            y += __shfl_xor(y, 1);        // quad reduce (DPP)
            y += __shfl_xor(y, 2);
            if (ns == 0)
                ((u16*)duS)[(l * DUS + dl) * 2] = f2b(y + uv * Dd);
        }
    }

    if (PHASE == 0) {
        *(float4*)(Pc + pqbase) = make_float4(P[0], P[1], P[2], P[3]);
        *(float4*)(Qc + pqbase) = make_float4(st[0], st[1], st[2], st[3]);
    } else {
        __syncthreads();
        for (int e = tid; e < CT * 8; e += 256) {
            const int l = e >> 3, g = e & 7;
            u16 t[8];
#pragma unroll
            for (int j = 0; j < 8; ++j)
                t[j] = (u16)(duS[l * DUS + g * 8 + j] & 0xFFFFu);
            *(u16x8*)((u16*)dy + (size_t)(row0 + l) * D_I + d0 + g * 8) =
                *(const u16x8*)t;
        }
    }
}

// Prefix over chunks. Sin may ALIAS Pc: all P/Q loaded to registers first.
__global__ __launch_bounds__(256) void scan_comb(
    const float* Pc, const float* Qc, float* Sin)
{
    const int b = blockIdx.y;
    const int d = blockIdx.x * 16 + (threadIdx.x >> 4);
    const int n = threadIdx.x & 15;
    const size_t i0 = (((size_t)b * CHNK) * D_I + d) * D_ST + n;
    const size_t cs = (size_t)D_I * D_ST;

    float p[CHNK], q[CHNK];
#pragma unroll
    for (int c = 0; c < CHNK; ++c) {
        p[c] = Pc[i0 + c * cs];
        q[c] = Qc[i0 + c * cs];
    }
    float s = 0.f;
#pragma unroll
    for (int c = 0; c < CHNK; ++c) {
        Sin[i0 + c * cs] = s;
        s = fmaf(s, p[c], q[c]);
    }
}

__global__ void zfill(float* o) {
    o[(size_t)blockIdx.x * 256 + threadIdx.x] = 0.f;
}

extern "C" void kernel_launch(void* const* d_in, const int* in_sizes, int n_in,
                              void* d_out, int out_size, void* d_ws, size_t ws_size,
                              hipStream_t stream)
{
    const float* hs   = (const float*)d_in[0];
    const float* Win  = (const float*)d_in[1];
    const float* cw   = (const float*)d_in[2];
    const float* cb   = (const float*)d_in[3];
    const float* Wx   = (const float*)d_in[4];
    const float* Wdt  = (const float*)d_in[5];
    const float* dtb  = (const float*)d_in[6];
    const float* Alog = (const float*)d_in[7];
    const float* Dp   = (const float*)d_in[8];
    const float* Wout = (const float*)d_in[9];
    float* out = (float*)d_out;

    const size_t SZ = (size_t)N_B * L_SEQ * D_I;        // 8,388,608
    const size_t NT = (size_t)N_B * L_SEQ;              // 4096 tokens
    const size_t NHS   = NT * D_M;
    const size_t NWIN  = (size_t)2 * D_I * D_M;
    const size_t NWOUT = (size_t)D_M * D_I;
    const size_t NWX   = (size_t)96 * D_I;
    const size_t NWDT  = (size_t)D_I * R_DT;
    const size_t NEED = SZ * 2 * sizeof(bf16)
                      + (NHS + NWIN + NWOUT + NWX + NWDT + NT * R_DT) * sizeof(u16)
                      + NT * 2 * D_ST * sizeof(float);
    if (ws_size < NEED) {   // diagnostic: absmax would print exactly 2.375
        zfill<<<dim3((unsigned)((size_t)out_size / 256)), 256, 0, stream>>>(out);
        return;
    }

    bf16* RA   = (bf16*)d_ws;          // x -> delta -> y(gated)
    bf16* RB   = RA + SZ;              // u -> z
    u16* bhs   = (u16*)(RB + SZ);
    u16* bWin  = bhs + NHS;
    u16* bWout = bWin + NWIN;
    u16* bWx   = bWout + NWOUT;
    u16* bWdt  = bWx + NWX;
    u16* dtlr  = bWdt + NWDT;
    float* Bm  = (float*)(dtlr + NT * R_DT);
    float* Cm  = Bm + NT * D_ST;
    float* Part = out;                 // d_out scratch (dead until final GEMM)
    const size_t PQ = (size_t)N_B * CHNK * D_I * D_ST;  // 2,097,152 floats (8MB)
    float* Pc  = out;                  // Pc+Qc = 16MB <= 16.78MB d_out
    float* Qc  = Pc + PQ;
    float* Sin = Pc;                   // ALIAS: comb reads P/Q to regs first

    // 0) one-time fp32 -> bf16 conversions
    cvt_k<<<dim3((unsigned)(NHS / 2048)), 256, 0, stream>>>(hs, bhs);
    cvt_k<<<dim3((unsigned)(NWIN / 2048)), 256, 0, stream>>>(Win, bWin);
    cvt_k<<<dim3((unsigned)(NWOUT / 2048)), 256, 0, stream>>>(Wout, bWout);
    cvt_k<<<dim3((unsigned)(NWX / 2048)), 256, 0, stream>>>(Wx, bWx);
    cvt_k<<<dim3((unsigned)(NWDT / 2048)), 256, 0, stream>>>(Wdt, bWdt);
    // 1) in_proj x-half
    bgemm<0><<<dim3(32, 16), 256, 0, stream>>>(
        bhs, D_M, bWin, D_M, D_M, (u16*)RA, nullptr, nullptr);
    // 2) conv + silu: RA(x) -> RB(u)
    conv_k<<<dim3(N_B * L_SEQ), 256, 0, stream>>>(RA, cw, cb, RB);
    // 3) x_proj split-K -> Part -> reduce
    xproj_k<<<dim3(64, KS), 256, 0, stream>>>((const u16*)RB, bWx, Part);
    xreduce<<<dim3((unsigned)(NT * 96 / 256)), 256, 0, stream>>>(Part, dtlr, Bm, Cm);
    // 4) dt -> delta (RA)
    bgemm<2><<<dim3(32, 16), 256, 0, stream>>>(
        dtlr, R_DT, bWdt, R_DT, R_DT, (u16*)RA, nullptr, dtb);
    // 5) chunked scan
    scan_chunk<0><<<dim3(D_I / 64, N_B, CHNK), 256, 0, stream>>>(
        RA, RB, Bm, Cm, Alog, Dp, Pc, Qc, nullptr);
    scan_comb<<<dim3(D_I / 16, N_B), 256, 0, stream>>>(Pc, Qc, Sin);
    scan_chunk<1><<<dim3(D_I / 64, N_B, CHNK), 256, 0, stream>>>(
        RA, RB, Bm, Cm, Alog, Dp, nullptr, nullptr, Sin);
    // 6) in_proj z-half -> RB
    bgemm<0><<<dim3(32, 16), 256, 0, stream>>>(
        bhs, D_M, bWin + (size_t)D_I * D_M, D_M, D_M, (u16*)RB, nullptr, nullptr);
    // 6b) gate: y *= silu(z)
    gate_k<<<dim3((unsigned)(SZ / 2048)), 256, 0, stream>>>((u16*)RA, (const u16*)RB);
    // 7) out_proj -> d_out
    bgemm<1><<<dim3(32, 8), 256, 0, stream>>>(
        (const u16*)RA, D_I, bWout, D_I, D_I, nullptr, out, nullptr);
}